// Round 11
// baseline (775.515 us; speedup 1.0000x reference)
//
#include <hip/hip_runtime.h>
#include <hip/hip_bf16.h>
#include <math.h>

#define NTOK 2048

typedef short short8v __attribute__((ext_vector_type(8)));
typedef short short4v __attribute__((ext_vector_type(4)));
typedef float f32x4 __attribute__((ext_vector_type(4)));
typedef unsigned u32x4 __attribute__((ext_vector_type(4)));

__device__ __forceinline__ unsigned short f2bf(float x){
  unsigned u = __float_as_uint(x);
  u += 0x7fff + ((u>>16)&1);           // round-to-nearest-even
  return (unsigned short)(u>>16);
}
__device__ __forceinline__ unsigned pack_bf2(float a, float b){
  __hip_bfloat162 h = __float22bfloat162_rn(float2{a,b});   // x -> low 16, y -> high 16
  return *reinterpret_cast<unsigned*>(&h);
}

// ---------------- compile-time G(3,0,1) tables ----------------
struct GEnt { unsigned char i, j, k; signed char s; };

constexpr int IDX2MASK[16] = {0,1,2,4,8,3,5,9,6,10,12,7,11,13,14,15};
constexpr int MASK2IDX[16] = {0,1,2,5,3,6,8,11,4,7,9,12,10,13,14,15};

constexpr int rsign(int a, int b){
  int cnt=0;
  for(int i=0;i<4;++i) if((b>>i)&1) for(int j=i+1;j<4;++j) if((a>>j)&1) cnt++;
  return (cnt&1)?-1:1;
}

struct GPTab { GEnt e[192]; };
constexpr GPTab make_gp(){
  GPTab t{}; int n=0;
  for(int ia=0; ia<16; ++ia) for(int ib=0; ib<16; ++ib){
    int a=IDX2MASK[ia], b=IDX2MASK[ib];
    if(a&b&1) continue;
    t.e[n].i=(unsigned char)ia; t.e[n].j=(unsigned char)ib;
    t.e[n].k=(unsigned char)MASK2IDX[a^b]; t.e[n].s=(signed char)rsign(a,b);
    ++n;
  }
  return t;
}
static constexpr GPTab GP_TAB = make_gp();

struct JTab { GEnt e[81]; };
constexpr JTab make_join(){
  JTab t{}; int n=0;
  for(int ia=0; ia<16; ++ia) for(int ib=0; ib<16; ++ib){
    int a=IDX2MASK[ia], b=IDX2MASK[ib];
    if((a|b)!=15) continue;
    int ca=(~a)&15, cb=(~b)&15, k=a&b, ck=(~k)&15;
    int s = rsign(a,ca)*rsign(b,cb)*rsign(ca,cb)*rsign(k,ck);
    t.e[n].i=(unsigned char)ia; t.e[n].j=(unsigned char)ib;
    t.e[n].k=(unsigned char)MASK2IDX[k]; t.e[n].s=(signed char)s;
    ++n;
  }
  return t;
}
static constexpr JTab J_TAB = make_join();

constexpr int INNER[8] = {0,2,3,4,8,9,10,14};

__device__ __forceinline__ void apply_gp(float* o, const float* a, const float* b){
#pragma unroll
  for(int n=0;n<192;++n){
    const float s = (float)GP_TAB.e[n].s;
    o[GP_TAB.e[n].k] = fmaf(s*a[GP_TAB.e[n].i], b[GP_TAB.e[n].j], o[GP_TAB.e[n].k]);
  }
}
__device__ __forceinline__ void apply_join(float* o, const float* a, const float* b){
#pragma unroll
  for(int n=0;n<81;++n){
    const float s = (float)J_TAB.e[n].s;
    o[J_TAB.e[n].k] = fmaf(s*a[J_TAB.e[n].i], b[J_TAB.e[n].j], o[J_TAB.e[n].k]);
  }
}

__device__ __forceinline__ void elin_row(float acc[16], const float* xin, const float* w0p){
#pragma unroll
  for(int j=0;j<16;++j) acc[j]=0.0f;
#pragma unroll
  for(int i=0;i<16;++i){
    const float* w = w0p + i*9;
    const float4* xp = (const float4*)(xin + i*16);
    float4 A=xp[0], B=xp[1], Cc=xp[2], D=xp[3];
    float w0=w[0],w1=w[1],w2=w[2],w3=w[3],w4=w[4],w5=w[5],w6=w[6],w7=w[7],w8=w[8];
    acc[0] = fmaf(w0, A.x,  acc[0]);
    acc[1] = fmaf(w1, A.y,  acc[1]);
    acc[2] = fmaf(w1, A.z,  acc[2]);
    acc[3] = fmaf(w1, A.w,  acc[3]);
    acc[4] = fmaf(w1, B.x,  acc[4]);
    acc[5] = fmaf(w2, B.y,  acc[5]);
    acc[6] = fmaf(w2, B.z,  acc[6]);
    acc[7] = fmaf(w2, B.w,  acc[7]);
    acc[8] = fmaf(w2, Cc.x, acc[8]);
    acc[9] = fmaf(w2, Cc.y, acc[9]);
    acc[10]= fmaf(w2, Cc.z, acc[10]);
    acc[11]= fmaf(w3, Cc.w, acc[11]);
    acc[12]= fmaf(w3, D.x,  acc[12]);
    acc[13]= fmaf(w3, D.y,  acc[13]);
    acc[14]= fmaf(w3, D.z,  acc[14]);
    acc[15]= fmaf(w4, D.w,  acc[15]);
    acc[1] = fmaf(w5, A.x,  acc[1]);
    acc[5] = fmaf(w6, A.z,  acc[5]);
    acc[6] = fmaf(w6, A.w,  acc[6]);
    acc[7] = fmaf(w6, B.x,  acc[7]);
    acc[11]= fmaf(w7, Cc.x, acc[11]);
    acc[12]= fmaf(w7, Cc.y, acc[12]);
    acc[13]= fmaf(w7, Cc.z, acc[13]);
    acc[15]= fmaf(w8, D.z,  acc[15]);
  }
}

__device__ __forceinline__ float gelu_exact(float x){
  return 0.5f*x*(1.0f+erff(x*0.70710678118654752f));
}

#define WPAD 145
#define TBS  264
#define TPB  8

// MODE 0: embed + W_in, norm + QKV(layer0). MODE 1: Wo+res, norm, MLP(+res), norm, QKV.
// MODE 2: Wo+res, norm, MLP(+res), W_out partial.
template<int MODE>
__global__ __launch_bounds__(128) void token_kernel(
    const float* __restrict__ points, const float* __restrict__ Win,
    const float* __restrict__ Wo, const float* __restrict__ Wl,
    const float* __restrict__ Wr, const float* __restrict__ Wm,
    const float* __restrict__ Wq, const float* __restrict__ Wk,
    const float* __restrict__ Wv, const float* __restrict__ Wout,
    const float* __restrict__ ATT, float* __restrict__ X,
    unsigned short* __restrict__ Qg16, unsigned short* __restrict__ Kg16,
    unsigned short* __restrict__ VgT, float* __restrict__ toksum)
{
  __shared__ float wlds[6*16*WPAD];
  __shared__ float buf[TPB*TBS];
  __shared__ float sred[TPB*16];
  const int tid = threadIdx.x;
  const int t = tid>>4, o = tid&15;
  const int n = blockIdx.x*TPB + t;

  auto stage = [&](float* dst, const float* src){
#pragma unroll
    for(int r=0;r<18;++r){
      int k = tid + r*128;
      dst[(k/144)*WPAD + (k%144)] = src[k];
    }
  };
  if (MODE==0){ stage(wlds+3*16*WPAD, Wq); stage(wlds+4*16*WPAD, Wk); stage(wlds+5*16*WPAD, Wv); }
  if (MODE==1){ stage(wlds+0*16*WPAD, Wl); stage(wlds+1*16*WPAD, Wr); stage(wlds+2*16*WPAD, Wm);
                stage(wlds+3*16*WPAD, Wq); stage(wlds+4*16*WPAD, Wk); stage(wlds+5*16*WPAD, Wv); }
  if (MODE==2){ stage(wlds+0*16*WPAD, Wl); stage(wlds+1*16*WPAD, Wr); stage(wlds+2*16*WPAD, Wm); }

  float* tb = buf + t*TBS;
  float xr[16];

  if (MODE==0){
    float px = points[n*3+0], py = points[n*3+1], pz = points[n*3+2];
    float w3 = Win[o*9+3], w8 = Win[o*9+8];
#pragma unroll
    for(int j=0;j<16;++j) xr[j]=0.0f;
    xr[11]= w3*pz; xr[12]= -w3*py; xr[13]= w3*px; xr[14]= w3; xr[15]= w8;
    float4* xg = (float4*)(X + (size_t)n*256 + o*16);
    xg[0]=make_float4(xr[0],xr[1],xr[2],xr[3]);
    xg[1]=make_float4(xr[4],xr[5],xr[6],xr[7]);
    xg[2]=make_float4(xr[8],xr[9],xr[10],xr[11]);
    xg[3]=make_float4(xr[12],xr[13],xr[14],xr[15]);
  } else {
    const float4* xg = (const float4*)(X + (size_t)n*256 + o*16);
    float4 a=xg[0],b=xg[1],c=xg[2],d=xg[3];
    xr[0]=a.x; xr[1]=a.y; xr[2]=a.z; xr[3]=a.w;
    xr[4]=b.x; xr[5]=b.y; xr[6]=b.z; xr[7]=b.w;
    xr[8]=c.x; xr[9]=c.y; xr[10]=c.z; xr[11]=c.w;
    xr[12]=d.x; xr[13]=d.y; xr[14]=d.z; xr[15]=d.w;
    const float4* ag = (const float4*)(ATT + (size_t)n*256 + o*16);
    float4* bp = (float4*)(tb + o*16);
    bp[0]=ag[0]; bp[1]=ag[1]; bp[2]=ag[2]; bp[3]=ag[3];
    __syncthreads();
    float acc[16];
    elin_row(acc, tb, Wo + o*144);
#pragma unroll
    for(int j=0;j<16;++j) xr[j]+=acc[j];
    float s=0;
#pragma unroll
    for(int z=0;z<8;++z){ float v=xr[INNER[z]]; s=fmaf(v,v,s); }
    sred[tid]=s; __syncthreads();
    float tot=0;
#pragma unroll
    for(int c2=0;c2<16;++c2) tot += sred[t*16+c2];
    float f = 1.0f/sqrtf(tot*(1.0f/16.0f)+1e-6f);
    float4* bp2=(float4*)(tb+o*16);
    bp2[0]=make_float4(xr[0]*f,xr[1]*f,xr[2]*f,xr[3]*f);
    bp2[1]=make_float4(xr[4]*f,xr[5]*f,xr[6]*f,xr[7]*f);
    bp2[2]=make_float4(xr[8]*f,xr[9]*f,xr[10]*f,xr[11]*f);
    bp2[3]=make_float4(xr[12]*f,xr[13]*f,xr[14]*f,xr[15]*f);
    __syncthreads();
    float L[16], R[16];
    elin_row(L, tb, wlds+0*16*WPAD + o*WPAD);
    elin_row(R, tb, wlds+1*16*WPAD + o*WPAD);
    float h[16];
#pragma unroll
    for(int j=0;j<16;++j) h[j]=0.0f;
    if (o<8) apply_gp(h,L,R); else apply_join(h,L,R);
    float gel = gelu_exact(h[0]);
#pragma unroll
    for(int j=0;j<16;++j) h[j]*=gel;
    __syncthreads();
    float4* bp3=(float4*)(tb+o*16);
    bp3[0]=make_float4(h[0],h[1],h[2],h[3]);
    bp3[1]=make_float4(h[4],h[5],h[6],h[7]);
    bp3[2]=make_float4(h[8],h[9],h[10],h[11]);
    bp3[3]=make_float4(h[12],h[13],h[14],h[15]);
    __syncthreads();
    float mm2[16];
    elin_row(mm2, tb, wlds+2*16*WPAD + o*WPAD);
#pragma unroll
    for(int j=0;j<16;++j) xr[j]+=mm2[j];
    if (MODE==1){
      float4* xs = (float4*)(X + (size_t)n*256 + o*16);
      xs[0]=make_float4(xr[0],xr[1],xr[2],xr[3]);
      xs[1]=make_float4(xr[4],xr[5],xr[6],xr[7]);
      xs[2]=make_float4(xr[8],xr[9],xr[10],xr[11]);
      xs[3]=make_float4(xr[12],xr[13],xr[14],xr[15]);
    }
  }

  if (MODE==2){
    sred[tid] = Wout[o*9]*xr[0];
    __syncthreads();
    if (o==0){
      float s2=0;
#pragma unroll
      for(int c2=0;c2<16;++c2) s2+=sred[t*16+c2];
      toksum[n]=s2;
    }
    return;
  }

  // ---- norm2 + QKV (bf16 outputs for MFMA attention) ----
  {
    float s=0;
#pragma unroll
    for(int z=0;z<8;++z){ float v=xr[INNER[z]]; s=fmaf(v,v,s); }
    sred[tid]=s; __syncthreads();
    float tot=0;
#pragma unroll
    for(int c2=0;c2<16;++c2) tot += sred[t*16+c2];
    float f2 = 1.0f/sqrtf(tot*(1.0f/16.0f)+1e-6f);
    float4* bp4=(float4*)(tb+o*16);
    bp4[0]=make_float4(xr[0]*f2,xr[1]*f2,xr[2]*f2,xr[3]*f2);
    bp4[1]=make_float4(xr[4]*f2,xr[5]*f2,xr[6]*f2,xr[7]*f2);
    bp4[2]=make_float4(xr[8]*f2,xr[9]*f2,xr[10]*f2,xr[11]*f2);
    bp4[3]=make_float4(xr[12]*f2,xr[13]*f2,xr[14]*f2,xr[15]*f2);
    __syncthreads();
    float q_[16],k_[16],v_[16];
    elin_row(q_, tb, wlds+3*16*WPAD+o*WPAD);
    elin_row(k_, tb, wlds+4*16*WPAD+o*WPAD);
    elin_row(v_, tb, wlds+5*16*WPAD+o*WPAD);
    int hh=o>>1, cc=o&1;
    {
      unsigned qw[4], kw[4];
#pragma unroll
      for(int j=0;j<4;++j){
        unsigned short a0=f2bf(q_[INNER[2*j]]*0.25f), a1=f2bf(q_[INNER[2*j+1]]*0.25f);
        unsigned short b0=f2bf(k_[INNER[2*j]]),       b1=f2bf(k_[INNER[2*j+1]]);
        qw[j] = (unsigned)a0 | ((unsigned)a1<<16);
        kw[j] = (unsigned)b0 | ((unsigned)b1<<16);
      }
      size_t rb = ((size_t)hh*NTOK + n)*16 + cc*8;
      *(uint4*)(Qg16 + rb) = make_uint4(qw[0],qw[1],qw[2],qw[3]);
      *(uint4*)(Kg16 + rb) = make_uint4(kw[0],kw[1],kw[2],kw[3]);
    }
    // V: bounce through LDS to write transposed bf16 VgT[h][32][n]
    __syncthreads();                     // all elin_row reads of tb done
    {
      float4* vb = (float4*)(tb + o*16);
      vb[0]=make_float4(v_[0],v_[1],v_[2],v_[3]);
      vb[1]=make_float4(v_[4],v_[5],v_[6],v_[7]);
      vb[2]=make_float4(v_[8],v_[9],v_[10],v_[11]);
      vb[3]=make_float4(v_[12],v_[13],v_[14],v_[15]);
    }
    __syncthreads();
#pragma unroll
    for(int pp=0;pp<2;++pp){
      int p  = tid + pp*128;             // 256 (h,v) rows / 128 threads
      int h2 = p>>5, v2 = p&31;
      int oc = 2*h2 + (v2>>4), c2 = v2&15;
      unsigned vw[4];
#pragma unroll
      for(int j=0;j<4;++j){
        unsigned short e0=f2bf(buf[(2*j  )*TBS + oc*16 + c2]);
        unsigned short e1=f2bf(buf[(2*j+1)*TBS + oc*16 + c2]);
        vw[j]=(unsigned)e0 | ((unsigned)e1<<16);
      }
      *(uint4*)(VgT + ((size_t)(h2*32+v2))*NTOK + (size_t)blockIdx.x*TPB) = make_uint4(vw[0],vw[1],vw[2],vw[3]);
    }
  }
}

// ---------------- MFMA flash attention: 8 waves/WG, two-pass, prefetched ----------------
// Grid 1024 = 8 heads x 128 q-tiles(16 q). Block 512 = 8 waves = 8 key-splits of 256.
// 4 blocks/CU -> 32 waves/CU (100% occupancy; was 16). Per-wave serial chain halves
// (8 iterations total). Pass 2 prefetches next iteration's K/V fragments before
// computing the current one (no barriers to defeat the pipelining).
__global__ __launch_bounds__(512, 8) void attn_kernel(
    const unsigned short* __restrict__ Qg16, const unsigned short* __restrict__ Kg16,
    const unsigned short* __restrict__ VgT,  float* __restrict__ ATT)
{
  __shared__ float cmb[8*32*17];               // [wave][v=32][q pad 17] = 17.4 KB
  __shared__ float ml[8*16*2];                 // [wave][q]{m,l}
  const int tid = threadIdx.x;
  const int l   = tid & 63, w = tid >> 6;      // w = 0..7 key-split
  const int h   = blockIdx.x >> 7, qb = blockIdx.x & 127;
  const int l15 = l & 15, lg = l >> 4;

  const short4v z4 = {0,0,0,0};
  short8v qf;                                   // B-operand: row=q=l15
  {
    const short4v* qp = (const short4v*)(Qg16 + ((size_t)(h*NTOK + qb*16 + l15))*16 + lg*4);
    qf = __builtin_shufflevector(*qp, z4, 0,1,2,3,4,5,6,7);
  }

  const int key0 = w*256;
  const size_t vrow = ((size_t)(h*32 + l15))*NTOK;

  auto LOADK = [&](int kc, short8v (&kf)[4]){
#pragma unroll
    for(int t2=0;t2<4;++t2){
      const short4v* kp = (const short4v*)(Kg16 + ((size_t)(h*NTOK + key0 + kc + t2*16 + l15))*16 + lg*4);
      kf[t2] = __builtin_shufflevector(*kp, z4, 0,1,2,3,4,5,6,7);   // upper k zero-pad
    }
  };
  auto LOADV = [&](int kc, short8v (&vf)[4]){
    size_t vb0 = vrow + key0 + kc;
    size_t vb1 = vb0 + (size_t)16*NTOK;
    const short4v* a0 = (const short4v*)(VgT + vb0 + lg*4);
    const short4v* b0 = (const short4v*)(VgT + vb0 + 16 + lg*4);
    const short4v* c0 = (const short4v*)(VgT + vb0 + 32 + lg*4);
    const short4v* d0 = (const short4v*)(VgT + vb0 + 48 + lg*4);
    vf[0] = __builtin_shufflevector(*a0, *b0, 0,1,2,3,4,5,6,7);
    vf[1] = __builtin_shufflevector(*c0, *d0, 0,1,2,3,4,5,6,7);
    const short4v* a1 = (const short4v*)(VgT + vb1 + lg*4);
    const short4v* b1 = (const short4v*)(VgT + vb1 + 16 + lg*4);
    const short4v* c1 = (const short4v*)(VgT + vb1 + 32 + lg*4);
    const short4v* d1 = (const short4v*)(VgT + vb1 + 48 + lg*4);
    vf[2] = __builtin_shufflevector(*a1, *b1, 0,1,2,3,4,5,6,7);
    vf[3] = __builtin_shufflevector(*c1, *d1, 0,1,2,3,4,5,6,7);
  };

  // ---- pass 1: exact max over this wave's 256 keys (fully unrolled, loads hoistable) ----
  float mx = -INFINITY;
#pragma unroll
  for(int kc=0; kc<256; kc+=64){
    short8v kf[4];
    LOADK(kc, kf);
#pragma unroll
    for(int t2=0;t2<4;++t2){
      f32x4 z = {0,0,0,0};
      f32x4 S = __builtin_amdgcn_mfma_f32_16x16x32_bf16(kf[t2], qf, z, 0,0,0);
      mx = fmaxf(mx, fmaxf(fmaxf(S[0],S[1]), fmaxf(S[2],S[3])));
    }
  }
  mx = fmaxf(mx, __shfl_xor(mx, 16));
  mx = fmaxf(mx, __shfl_xor(mx, 32));
  const float M = mx;                           // exact split max for q=l15

  // ---- pass 2: accumulate with fixed M; prefetch next iteration's fragments ----
  f32x4 acc0 = {0,0,0,0}, acc1 = {0,0,0,0};    // O[q=lg*4+r][v=l15], v+16
  float ls = 0.0f;
  short8v kfc[4], vfc[4], kfn[4], vfn[4];
  LOADK(0, kfc); LOADV(0, vfc);
#pragma unroll
  for(int it=0; it<4; ++it){
    if (it<3){ LOADK((it+1)*64, kfn); LOADV((it+1)*64, vfn); }
    f32x4 S[4];
#pragma unroll
    for(int t2=0;t2<4;++t2){
      f32x4 z = {0,0,0,0};
      S[t2] = __builtin_amdgcn_mfma_f32_16x16x32_bf16(kfc[t2], qf, z, 0,0,0);
    }
    float p[4][4];
#pragma unroll
    for(int t2=0;t2<4;++t2)
#pragma unroll
      for(int r=0;r<4;++r){ float pv = __expf(S[t2][r]-M); p[t2][r]=pv; ls += pv; }
    u32x4 paw, paw2;
    paw[0]=pack_bf2(p[0][0],p[0][1]); paw[1]=pack_bf2(p[0][2],p[0][3]);
    paw[2]=pack_bf2(p[1][0],p[1][1]); paw[3]=pack_bf2(p[1][2],p[1][3]);
    paw2[0]=pack_bf2(p[2][0],p[2][1]); paw2[1]=pack_bf2(p[2][2],p[2][3]);
    paw2[2]=pack_bf2(p[3][0],p[3][1]); paw2[3]=pack_bf2(p[3][2],p[3][3]);
    short8v pa  = *reinterpret_cast<short8v*>(&paw);
    short8v pa2 = *reinterpret_cast<short8v*>(&paw2);
    acc0 = __builtin_amdgcn_mfma_f32_16x16x32_bf16(pa,  vfc[0], acc0, 0,0,0);
    acc0 = __builtin_amdgcn_mfma_f32_16x16x32_bf16(pa2, vfc[1], acc0, 0,0,0);
    acc1 = __builtin_amdgcn_mfma_f32_16x16x32_bf16(pa,  vfc[2], acc1, 0,0,0);
    acc1 = __builtin_amdgcn_mfma_f32_16x16x32_bf16(pa2, vfc[3], acc1, 0,0,0);
#pragma unroll
    for(int z2=0;z2<4;++z2){ kfc[z2]=kfn[z2]; vfc[z2]=vfn[z2]; }
  }
  ls += __shfl_xor(ls, 16);
  ls += __shfl_xor(ls, 32);

  // ---- 8-way key-split combine ----
  {
    float* cw = cmb + w*544;
#pragma unroll
    for(int r=0;r<4;++r){
      cw[ l15     *17 + lg*4 + r] = acc0[r];
      cw[(l15+16) *17 + lg*4 + r] = acc1[r];
    }
    if (lg == 0){
      ml[(w*16 + l15)*2]   = M;
      ml[(w*16 + l15)*2+1] = ls;
    }
  }
  __syncthreads();
  {
    int q = tid & 15, v = tid >> 4;       // v in 0..31; one output per thread
    float Mg = -INFINITY;
#pragma unroll
    for(int w2=0; w2<8; ++w2) Mg = fmaxf(Mg, ml[(w2*16+q)*2]);
    float L=0, a=0;
#pragma unroll
    for(int w2=0; w2<8; ++w2){
      float ww = __expf(ml[(w2*16+q)*2] - Mg);
      L = fmaf(ml[(w2*16+q)*2+1], ww, L);
      a = fmaf(cmb[w2*544 + v*17 + q], ww, a);
    }
    int n = qb*16 + q;
    ATT[(size_t)n*256 + (size_t)(2*h + (v>>4))*16 + (v&15)] = a/L;
  }
}

__global__ __launch_bounds__(256) void reduce_kernel(const float* __restrict__ tok, float* __restrict__ out){
  int tid=threadIdx.x;
  float s=0;
  for(int i=tid;i<NTOK;i+=256) s+=tok[i];
#pragma unroll
  for(int off=32;off>0;off>>=1) s += __shfl_down(s,off);
  __shared__ float red[4];
  if((tid&63)==0) red[tid>>6]=s;
  __syncthreads();
  if(tid==0) out[0]=(red[0]+red[1]+red[2]+red[3])*(1.0f/2048.0f);
}

extern "C" void kernel_launch(void* const* d_in, const int* in_sizes, int n_in,
                              void* d_out, int out_size, void* d_ws, size_t ws_size,
                              hipStream_t stream){
  const float* points=(const float*)d_in[0];
  const float* Win=(const float*)d_in[1];
  const float* Wq=(const float*)d_in[2];
  const float* Wk=(const float*)d_in[3];
  const float* Wv=(const float*)d_in[4];
  const float* Wo=(const float*)d_in[5];
  const float* Wl=(const float*)d_in[6];
  const float* Wr=(const float*)d_in[7];
  const float* Wm=(const float*)d_in[8];
  const float* Wout=(const float*)d_in[9];
  float* ws=(float*)d_ws;
  float* X    = ws;                                         // 524288 f
  float* ATT  = ws + 524288;                                // 524288 f
  unsigned short* Qg16 = (unsigned short*)(ws + 1048576);   // 262144 us
  unsigned short* Kg16 = (unsigned short*)(ws + 1179648);   // 262144 us
  unsigned short* VgT  = (unsigned short*)(ws + 1310720);   // 524288 us
  float* tok  = ws + 1572864;
  float* out=(float*)d_out;

  token_kernel<0><<<256,128,0,stream>>>(points,Win,nullptr,nullptr,nullptr,nullptr,
                                        Wq,Wk,Wv,nullptr,nullptr,X,Qg16,Kg16,VgT,nullptr);
  for(int l=0;l<10;++l){
    attn_kernel<<<1024,512,0,stream>>>(Qg16,Kg16,VgT,ATT);
    if(l<9){
      token_kernel<1><<<256,128,0,stream>>>(nullptr,nullptr,
          Wo+l*2304,Wl+l*2304,Wr+l*2304,Wm+l*2304,
          Wq+(l+1)*2304,Wk+(l+1)*2304,Wv+(l+1)*2304,nullptr,
          ATT,X,Qg16,Kg16,VgT,nullptr);
    } else {
      token_kernel<2><<<256,128,0,stream>>>(nullptr,nullptr,
          Wo+l*2304,Wl+l*2304,Wr+l*2304,Wm+l*2304,
          nullptr,nullptr,nullptr,Wout,
          ATT,X,nullptr,nullptr,nullptr,tok);
    }
  }
  reduce_kernel<<<1,256,0,stream>>>(tok,out);
}

// Round 12
// 677.427 us; speedup vs baseline: 1.1448x; 1.1448x over previous
//
#include <hip/hip_runtime.h>
#include <hip/hip_bf16.h>
#include <math.h>

#define NTOK 2048

typedef short short8v __attribute__((ext_vector_type(8)));
typedef short short4v __attribute__((ext_vector_type(4)));
typedef float f32x4 __attribute__((ext_vector_type(4)));
typedef unsigned u32x4 __attribute__((ext_vector_type(4)));

__device__ __forceinline__ unsigned short f2bf(float x){
  unsigned u = __float_as_uint(x);
  u += 0x7fff + ((u>>16)&1);           // round-to-nearest-even
  return (unsigned short)(u>>16);
}
__device__ __forceinline__ unsigned pack_bf2(float a, float b){
  __hip_bfloat162 h = __float22bfloat162_rn(float2{a,b});   // x -> low 16, y -> high 16
  return *reinterpret_cast<unsigned*>(&h);
}

// ---------------- compile-time G(3,0,1) tables ----------------
struct GEnt { unsigned char i, j, k; signed char s; };

constexpr int IDX2MASK[16] = {0,1,2,4,8,3,5,9,6,10,12,7,11,13,14,15};
constexpr int MASK2IDX[16] = {0,1,2,5,3,6,8,11,4,7,9,12,10,13,14,15};

constexpr int rsign(int a, int b){
  int cnt=0;
  for(int i=0;i<4;++i) if((b>>i)&1) for(int j=i+1;j<4;++j) if((a>>j)&1) cnt++;
  return (cnt&1)?-1:1;
}

struct GPTab { GEnt e[192]; };
constexpr GPTab make_gp(){
  GPTab t{}; int n=0;
  for(int ia=0; ia<16; ++ia) for(int ib=0; ib<16; ++ib){
    int a=IDX2MASK[ia], b=IDX2MASK[ib];
    if(a&b&1) continue;
    t.e[n].i=(unsigned char)ia; t.e[n].j=(unsigned char)ib;
    t.e[n].k=(unsigned char)MASK2IDX[a^b]; t.e[n].s=(signed char)rsign(a,b);
    ++n;
  }
  return t;
}
static constexpr GPTab GP_TAB = make_gp();

struct JTab { GEnt e[81]; };
constexpr JTab make_join(){
  JTab t{}; int n=0;
  for(int ia=0; ia<16; ++ia) for(int ib=0; ib<16; ++ib){
    int a=IDX2MASK[ia], b=IDX2MASK[ib];
    if((a|b)!=15) continue;
    int ca=(~a)&15, cb=(~b)&15, k=a&b, ck=(~k)&15;
    int s = rsign(a,ca)*rsign(b,cb)*rsign(ca,cb)*rsign(k,ck);
    t.e[n].i=(unsigned char)ia; t.e[n].j=(unsigned char)ib;
    t.e[n].k=(unsigned char)MASK2IDX[k]; t.e[n].s=(signed char)s;
    ++n;
  }
  return t;
}
static constexpr JTab J_TAB = make_join();

constexpr int INNER[8] = {0,2,3,4,8,9,10,14};

__device__ __forceinline__ void apply_gp(float* o, const float* a, const float* b){
#pragma unroll
  for(int n=0;n<192;++n){
    const float s = (float)GP_TAB.e[n].s;
    o[GP_TAB.e[n].k] = fmaf(s*a[GP_TAB.e[n].i], b[GP_TAB.e[n].j], o[GP_TAB.e[n].k]);
  }
}
__device__ __forceinline__ void apply_join(float* o, const float* a, const float* b){
#pragma unroll
  for(int n=0;n<81;++n){
    const float s = (float)J_TAB.e[n].s;
    o[J_TAB.e[n].k] = fmaf(s*a[J_TAB.e[n].i], b[J_TAB.e[n].j], o[J_TAB.e[n].k]);
  }
}

__device__ __forceinline__ void elin_row(float acc[16], const float* xin, const float* w0p){
#pragma unroll
  for(int j=0;j<16;++j) acc[j]=0.0f;
#pragma unroll
  for(int i=0;i<16;++i){
    const float* w = w0p + i*9;
    const float4* xp = (const float4*)(xin + i*16);
    float4 A=xp[0], B=xp[1], Cc=xp[2], D=xp[3];
    float w0=w[0],w1=w[1],w2=w[2],w3=w[3],w4=w[4],w5=w[5],w6=w[6],w7=w[7],w8=w[8];
    acc[0] = fmaf(w0, A.x,  acc[0]);
    acc[1] = fmaf(w1, A.y,  acc[1]);
    acc[2] = fmaf(w1, A.z,  acc[2]);
    acc[3] = fmaf(w1, A.w,  acc[3]);
    acc[4] = fmaf(w1, B.x,  acc[4]);
    acc[5] = fmaf(w2, B.y,  acc[5]);
    acc[6] = fmaf(w2, B.z,  acc[6]);
    acc[7] = fmaf(w2, B.w,  acc[7]);
    acc[8] = fmaf(w2, Cc.x, acc[8]);
    acc[9] = fmaf(w2, Cc.y, acc[9]);
    acc[10]= fmaf(w2, Cc.z, acc[10]);
    acc[11]= fmaf(w3, Cc.w, acc[11]);
    acc[12]= fmaf(w3, D.x,  acc[12]);
    acc[13]= fmaf(w3, D.y,  acc[13]);
    acc[14]= fmaf(w3, D.z,  acc[14]);
    acc[15]= fmaf(w4, D.w,  acc[15]);
    acc[1] = fmaf(w5, A.x,  acc[1]);
    acc[5] = fmaf(w6, A.z,  acc[5]);
    acc[6] = fmaf(w6, A.w,  acc[6]);
    acc[7] = fmaf(w6, B.x,  acc[7]);
    acc[11]= fmaf(w7, Cc.x, acc[11]);
    acc[12]= fmaf(w7, Cc.y, acc[12]);
    acc[13]= fmaf(w7, Cc.z, acc[13]);
    acc[15]= fmaf(w8, D.z,  acc[15]);
  }
}

__device__ __forceinline__ float gelu_exact(float x){
  return 0.5f*x*(1.0f+erff(x*0.70710678118654752f));
}

#define WPAD 145
#define TBS  264
#define TPB  8

// MODE 0: embed + W_in, norm + QKV(layer0). MODE 1: Wo+res, norm, MLP(+res), norm, QKV.
// MODE 2: Wo+res, norm, MLP(+res), W_out partial.
template<int MODE>
__global__ __launch_bounds__(128) void token_kernel(
    const float* __restrict__ points, const float* __restrict__ Win,
    const float* __restrict__ Wo, const float* __restrict__ Wl,
    const float* __restrict__ Wr, const float* __restrict__ Wm,
    const float* __restrict__ Wq, const float* __restrict__ Wk,
    const float* __restrict__ Wv, const float* __restrict__ Wout,
    const float* __restrict__ ATT, float* __restrict__ X,
    unsigned short* __restrict__ Qg16, unsigned short* __restrict__ Kg16,
    unsigned short* __restrict__ VgT, float* __restrict__ toksum)
{
  __shared__ float wlds[6*16*WPAD];
  __shared__ float buf[TPB*TBS];
  __shared__ float sred[TPB*16];
  const int tid = threadIdx.x;
  const int t = tid>>4, o = tid&15;
  const int n = blockIdx.x*TPB + t;

  auto stage = [&](float* dst, const float* src){
#pragma unroll
    for(int r=0;r<18;++r){
      int k = tid + r*128;
      dst[(k/144)*WPAD + (k%144)] = src[k];
    }
  };
  if (MODE==0){ stage(wlds+3*16*WPAD, Wq); stage(wlds+4*16*WPAD, Wk); stage(wlds+5*16*WPAD, Wv); }
  if (MODE==1){ stage(wlds+0*16*WPAD, Wl); stage(wlds+1*16*WPAD, Wr); stage(wlds+2*16*WPAD, Wm);
                stage(wlds+3*16*WPAD, Wq); stage(wlds+4*16*WPAD, Wk); stage(wlds+5*16*WPAD, Wv); }
  if (MODE==2){ stage(wlds+0*16*WPAD, Wl); stage(wlds+1*16*WPAD, Wr); stage(wlds+2*16*WPAD, Wm); }

  float* tb = buf + t*TBS;
  float xr[16];

  if (MODE==0){
    float px = points[n*3+0], py = points[n*3+1], pz = points[n*3+2];
    float w3 = Win[o*9+3], w8 = Win[o*9+8];
#pragma unroll
    for(int j=0;j<16;++j) xr[j]=0.0f;
    xr[11]= w3*pz; xr[12]= -w3*py; xr[13]= w3*px; xr[14]= w3; xr[15]= w8;
    float4* xg = (float4*)(X + (size_t)n*256 + o*16);
    xg[0]=make_float4(xr[0],xr[1],xr[2],xr[3]);
    xg[1]=make_float4(xr[4],xr[5],xr[6],xr[7]);
    xg[2]=make_float4(xr[8],xr[9],xr[10],xr[11]);
    xg[3]=make_float4(xr[12],xr[13],xr[14],xr[15]);
  } else {
    const float4* xg = (const float4*)(X + (size_t)n*256 + o*16);
    float4 a=xg[0],b=xg[1],c=xg[2],d=xg[3];
    xr[0]=a.x; xr[1]=a.y; xr[2]=a.z; xr[3]=a.w;
    xr[4]=b.x; xr[5]=b.y; xr[6]=b.z; xr[7]=b.w;
    xr[8]=c.x; xr[9]=c.y; xr[10]=c.z; xr[11]=c.w;
    xr[12]=d.x; xr[13]=d.y; xr[14]=d.z; xr[15]=d.w;
    const float4* ag = (const float4*)(ATT + (size_t)n*256 + o*16);
    float4* bp = (float4*)(tb + o*16);
    bp[0]=ag[0]; bp[1]=ag[1]; bp[2]=ag[2]; bp[3]=ag[3];
    __syncthreads();
    float acc[16];
    elin_row(acc, tb, Wo + o*144);
#pragma unroll
    for(int j=0;j<16;++j) xr[j]+=acc[j];
    float s=0;
#pragma unroll
    for(int z=0;z<8;++z){ float v=xr[INNER[z]]; s=fmaf(v,v,s); }
    sred[tid]=s; __syncthreads();
    float tot=0;
#pragma unroll
    for(int c2=0;c2<16;++c2) tot += sred[t*16+c2];
    float f = 1.0f/sqrtf(tot*(1.0f/16.0f)+1e-6f);
    float4* bp2=(float4*)(tb+o*16);
    bp2[0]=make_float4(xr[0]*f,xr[1]*f,xr[2]*f,xr[3]*f);
    bp2[1]=make_float4(xr[4]*f,xr[5]*f,xr[6]*f,xr[7]*f);
    bp2[2]=make_float4(xr[8]*f,xr[9]*f,xr[10]*f,xr[11]*f);
    bp2[3]=make_float4(xr[12]*f,xr[13]*f,xr[14]*f,xr[15]*f);
    __syncthreads();
    float L[16], R[16];
    elin_row(L, tb, wlds+0*16*WPAD + o*WPAD);
    elin_row(R, tb, wlds+1*16*WPAD + o*WPAD);
    float h[16];
#pragma unroll
    for(int j=0;j<16;++j) h[j]=0.0f;
    if (o<8) apply_gp(h,L,R); else apply_join(h,L,R);
    float gel = gelu_exact(h[0]);
#pragma unroll
    for(int j=0;j<16;++j) h[j]*=gel;
    __syncthreads();
    float4* bp3=(float4*)(tb+o*16);
    bp3[0]=make_float4(h[0],h[1],h[2],h[3]);
    bp3[1]=make_float4(h[4],h[5],h[6],h[7]);
    bp3[2]=make_float4(h[8],h[9],h[10],h[11]);
    bp3[3]=make_float4(h[12],h[13],h[14],h[15]);
    __syncthreads();
    float mm2[16];
    elin_row(mm2, tb, wlds+2*16*WPAD + o*WPAD);
#pragma unroll
    for(int j=0;j<16;++j) xr[j]+=mm2[j];
    if (MODE==1){
      float4* xs = (float4*)(X + (size_t)n*256 + o*16);
      xs[0]=make_float4(xr[0],xr[1],xr[2],xr[3]);
      xs[1]=make_float4(xr[4],xr[5],xr[6],xr[7]);
      xs[2]=make_float4(xr[8],xr[9],xr[10],xr[11]);
      xs[3]=make_float4(xr[12],xr[13],xr[14],xr[15]);
    }
  }

  if (MODE==2){
    sred[tid] = Wout[o*9]*xr[0];
    __syncthreads();
    if (o==0){
      float s2=0;
#pragma unroll
      for(int c2=0;c2<16;++c2) s2+=sred[t*16+c2];
      toksum[n]=s2;
    }
    return;
  }

  // ---- norm2 + QKV (bf16 outputs for MFMA attention) ----
  {
    float s=0;
#pragma unroll
    for(int z=0;z<8;++z){ float v=xr[INNER[z]]; s=fmaf(v,v,s); }
    sred[tid]=s; __syncthreads();
    float tot=0;
#pragma unroll
    for(int c2=0;c2<16;++c2) tot += sred[t*16+c2];
    float f2 = 1.0f/sqrtf(tot*(1.0f/16.0f)+1e-6f);
    float4* bp4=(float4*)(tb+o*16);
    bp4[0]=make_float4(xr[0]*f2,xr[1]*f2,xr[2]*f2,xr[3]*f2);
    bp4[1]=make_float4(xr[4]*f2,xr[5]*f2,xr[6]*f2,xr[7]*f2);
    bp4[2]=make_float4(xr[8]*f2,xr[9]*f2,xr[10]*f2,xr[11]*f2);
    bp4[3]=make_float4(xr[12]*f2,xr[13]*f2,xr[14]*f2,xr[15]*f2);
    __syncthreads();
    float q_[16],k_[16],v_[16];
    elin_row(q_, tb, wlds+3*16*WPAD+o*WPAD);
    elin_row(k_, tb, wlds+4*16*WPAD+o*WPAD);
    elin_row(v_, tb, wlds+5*16*WPAD+o*WPAD);
    int hh=o>>1, cc=o&1;
    {
      unsigned qw[4], kw[4];
#pragma unroll
      for(int j=0;j<4;++j){
        unsigned short a0=f2bf(q_[INNER[2*j]]*0.25f), a1=f2bf(q_[INNER[2*j+1]]*0.25f);
        unsigned short b0=f2bf(k_[INNER[2*j]]),       b1=f2bf(k_[INNER[2*j+1]]);
        qw[j] = (unsigned)a0 | ((unsigned)a1<<16);
        kw[j] = (unsigned)b0 | ((unsigned)b1<<16);
      }
      size_t rb = ((size_t)hh*NTOK + n)*16 + cc*8;
      *(uint4*)(Qg16 + rb) = make_uint4(qw[0],qw[1],qw[2],qw[3]);
      *(uint4*)(Kg16 + rb) = make_uint4(kw[0],kw[1],kw[2],kw[3]);
    }
    // V: bounce through LDS to write transposed bf16 VgT[h][32][n]
    __syncthreads();                     // all elin_row reads of tb done
    {
      float4* vb = (float4*)(tb + o*16);
      vb[0]=make_float4(v_[0],v_[1],v_[2],v_[3]);
      vb[1]=make_float4(v_[4],v_[5],v_[6],v_[7]);
      vb[2]=make_float4(v_[8],v_[9],v_[10],v_[11]);
      vb[3]=make_float4(v_[12],v_[13],v_[14],v_[15]);
    }
    __syncthreads();
#pragma unroll
    for(int pp=0;pp<2;++pp){
      int p  = tid + pp*128;             // 256 (h,v) rows / 128 threads
      int h2 = p>>5, v2 = p&31;
      int oc = 2*h2 + (v2>>4), c2 = v2&15;
      unsigned vw[4];
#pragma unroll
      for(int j=0;j<4;++j){
        unsigned short e0=f2bf(buf[(2*j  )*TBS + oc*16 + c2]);
        unsigned short e1=f2bf(buf[(2*j+1)*TBS + oc*16 + c2]);
        vw[j]=(unsigned)e0 | ((unsigned)e1<<16);
      }
      *(uint4*)(VgT + ((size_t)(h2*32+v2))*NTOK + (size_t)blockIdx.x*TPB) = make_uint4(vw[0],vw[1],vw[2],vw[3]);
    }
  }
}

// ---------------- MFMA flash attention: 8 waves/WG, two-pass, NO explicit prefetch ----------------
// Grid 1024 = 8 heads x 128 q-tiles(16 q). Block 512 = 8 waves = 8 key-splits of 256.
// r11 lesson: launch_bounds(512,8) + 64-VGPR prefetch arrays => VGPR=32 + scratch
// spills (82 MB writes/dispatch). Fix: r10 inner structure (compiles to ~48 VGPR,
// fits the 64-VGPR/8-wave budget), unroll 1, TLP (8 waves/SIMD) hides latency.
__global__ __launch_bounds__(512, 8) void attn_kernel(
    const unsigned short* __restrict__ Qg16, const unsigned short* __restrict__ Kg16,
    const unsigned short* __restrict__ VgT,  float* __restrict__ ATT)
{
  __shared__ float cmb[8*32*17];               // [wave][v=32][q pad 17] = 17.4 KB
  __shared__ float ml[8*16*2];                 // [wave][q]{m,l}
  const int tid = threadIdx.x;
  const int l   = tid & 63, w = tid >> 6;      // w = 0..7 key-split
  const int h   = blockIdx.x >> 7, qb = blockIdx.x & 127;
  const int l15 = l & 15, lg = l >> 4;

  const short4v z4 = {0,0,0,0};
  short8v qf;                                   // B-operand: row=q=l15
  {
    const short4v* qp = (const short4v*)(Qg16 + ((size_t)(h*NTOK + qb*16 + l15))*16 + lg*4);
    qf = __builtin_shufflevector(*qp, z4, 0,1,2,3,4,5,6,7);
  }

  const int key0 = w*256;
  const size_t vrow = ((size_t)(h*32 + l15))*NTOK;

  // ---- pass 1: exact max over this wave's 256 keys ----
  float mx = -INFINITY;
#pragma unroll 1
  for(int kc=0; kc<256; kc+=64){
#pragma unroll
    for(int t2=0;t2<4;++t2){
      const short4v* kp = (const short4v*)(Kg16 + ((size_t)(h*NTOK + key0 + kc + t2*16 + l15))*16 + lg*4);
      short8v kf = __builtin_shufflevector(*kp, z4, 0,1,2,3,4,5,6,7);
      f32x4 z = {0,0,0,0};
      f32x4 S = __builtin_amdgcn_mfma_f32_16x16x32_bf16(kf, qf, z, 0,0,0);
      mx = fmaxf(mx, fmaxf(fmaxf(S[0],S[1]), fmaxf(S[2],S[3])));
    }
  }
  mx = fmaxf(mx, __shfl_xor(mx, 16));
  mx = fmaxf(mx, __shfl_xor(mx, 32));
  const float M = mx;                           // exact split max for q=l15

  // ---- pass 2: accumulate with fixed M (no cross-lane ops in loop) ----
  f32x4 acc0 = {0,0,0,0}, acc1 = {0,0,0,0};    // O[q=lg*4+r][v=l15], v+16
  float ls = 0.0f;
#pragma unroll 1
  for(int kc=0; kc<256; kc+=64){
    f32x4 S[4];
#pragma unroll
    for(int t2=0;t2<4;++t2){
      const short4v* kp = (const short4v*)(Kg16 + ((size_t)(h*NTOK + key0 + kc + t2*16 + l15))*16 + lg*4);
      short8v kf = __builtin_shufflevector(*kp, z4, 0,1,2,3,4,5,6,7);
      f32x4 z = {0,0,0,0};
      S[t2] = __builtin_amdgcn_mfma_f32_16x16x32_bf16(kf, qf, z, 0,0,0);
    }
    float p[4][4];
#pragma unroll
    for(int t2=0;t2<4;++t2)
#pragma unroll
      for(int r=0;r<4;++r){ float pv = __expf(S[t2][r]-M); p[t2][r]=pv; ls += pv; }
    u32x4 paw, paw2;
    paw[0]=pack_bf2(p[0][0],p[0][1]); paw[1]=pack_bf2(p[0][2],p[0][3]);
    paw[2]=pack_bf2(p[1][0],p[1][1]); paw[3]=pack_bf2(p[1][2],p[1][3]);
    paw2[0]=pack_bf2(p[2][0],p[2][1]); paw2[1]=pack_bf2(p[2][2],p[2][3]);
    paw2[2]=pack_bf2(p[3][0],p[3][1]); paw2[3]=pack_bf2(p[3][2],p[3][3]);
    short8v pa  = *reinterpret_cast<short8v*>(&paw);
    short8v pa2 = *reinterpret_cast<short8v*>(&paw2);
    size_t vb = vrow + key0 + kc;
    const short4v* v0a = (const short4v*)(VgT + vb + lg*4);
    const short4v* v0b = (const short4v*)(VgT + vb + 16 + lg*4);
    const short4v* v0c = (const short4v*)(VgT + vb + 32 + lg*4);
    const short4v* v0d = (const short4v*)(VgT + vb + 48 + lg*4);
    short8v vb0  = __builtin_shufflevector(*v0a, *v0b, 0,1,2,3,4,5,6,7);
    short8v vb0b = __builtin_shufflevector(*v0c, *v0d, 0,1,2,3,4,5,6,7);
    size_t vb1s = vb + (size_t)16*NTOK;
    const short4v* v1a = (const short4v*)(VgT + vb1s + lg*4);
    const short4v* v1b = (const short4v*)(VgT + vb1s + 16 + lg*4);
    const short4v* v1c = (const short4v*)(VgT + vb1s + 32 + lg*4);
    const short4v* v1d = (const short4v*)(VgT + vb1s + 48 + lg*4);
    short8v vb1  = __builtin_shufflevector(*v1a, *v1b, 0,1,2,3,4,5,6,7);
    short8v vb1b = __builtin_shufflevector(*v1c, *v1d, 0,1,2,3,4,5,6,7);
    acc0 = __builtin_amdgcn_mfma_f32_16x16x32_bf16(pa,  vb0,  acc0, 0,0,0);
    acc0 = __builtin_amdgcn_mfma_f32_16x16x32_bf16(pa2, vb0b, acc0, 0,0,0);
    acc1 = __builtin_amdgcn_mfma_f32_16x16x32_bf16(pa,  vb1,  acc1, 0,0,0);
    acc1 = __builtin_amdgcn_mfma_f32_16x16x32_bf16(pa2, vb1b, acc1, 0,0,0);
  }
  ls += __shfl_xor(ls, 16);
  ls += __shfl_xor(ls, 32);

  // ---- 8-way key-split combine ----
  {
    float* cw = cmb + w*544;
#pragma unroll
    for(int r=0;r<4;++r){
      cw[ l15     *17 + lg*4 + r] = acc0[r];
      cw[(l15+16) *17 + lg*4 + r] = acc1[r];
    }
    if (lg == 0){
      ml[(w*16 + l15)*2]   = M;
      ml[(w*16 + l15)*2+1] = ls;
    }
  }
  __syncthreads();
  {
    int q = tid & 15, v = tid >> 4;       // v in 0..31; one output per thread
    float Mg = -INFINITY;
#pragma unroll
    for(int w2=0; w2<8; ++w2) Mg = fmaxf(Mg, ml[(w2*16+q)*2]);
    float L=0, a=0;
#pragma unroll
    for(int w2=0; w2<8; ++w2){
      float ww = __expf(ml[(w2*16+q)*2] - Mg);
      L = fmaf(ml[(w2*16+q)*2+1], ww, L);
      a = fmaf(cmb[w2*544 + v*17 + q], ww, a);
    }
    int n = qb*16 + q;
    ATT[(size_t)n*256 + (size_t)(2*h + (v>>4))*16 + (v&15)] = a/L;
  }
}

__global__ __launch_bounds__(256) void reduce_kernel(const float* __restrict__ tok, float* __restrict__ out){
  int tid=threadIdx.x;
  float s=0;
  for(int i=tid;i<NTOK;i+=256) s+=tok[i];
#pragma unroll
  for(int off=32;off>0;off>>=1) s += __shfl_down(s,off);
  __shared__ float red[4];
  if((tid&63)==0) red[tid>>6]=s;
  __syncthreads();
  if(tid==0) out[0]=(red[0]+red[1]+red[2]+red[3])*(1.0f/2048.0f);
}

extern "C" void kernel_launch(void* const* d_in, const int* in_sizes, int n_in,
                              void* d_out, int out_size, void* d_ws, size_t ws_size,
                              hipStream_t stream){
  const float* points=(const float*)d_in[0];
  const float* Win=(const float*)d_in[1];
  const float* Wq=(const float*)d_in[2];
  const float* Wk=(const float*)d_in[3];
  const float* Wv=(const float*)d_in[4];
  const float* Wo=(const float*)d_in[5];
  const float* Wl=(const float*)d_in[6];
  const float* Wr=(const float*)d_in[7];
  const float* Wm=(const float*)d_in[8];
  const float* Wout=(const float*)d_in[9];
  float* ws=(float*)d_ws;
  float* X    = ws;                                         // 524288 f
  float* ATT  = ws + 524288;                                // 524288 f
  unsigned short* Qg16 = (unsigned short*)(ws + 1048576);   // 262144 us
  unsigned short* Kg16 = (unsigned short*)(ws + 1179648);   // 262144 us
  unsigned short* VgT  = (unsigned short*)(ws + 1310720);   // 524288 us
  float* tok  = ws + 1572864;
  float* out=(float*)d_out;

  token_kernel<0><<<256,128,0,stream>>>(points,Win,nullptr,nullptr,nullptr,nullptr,
                                        Wq,Wk,Wv,nullptr,nullptr,X,Qg16,Kg16,VgT,nullptr);
  for(int l=0;l<10;++l){
    attn_kernel<<<1024,512,0,stream>>>(Qg16,Kg16,VgT,ATT);
    if(l<9){
      token_kernel<1><<<256,128,0,stream>>>(nullptr,nullptr,
          Wo+l*2304,Wl+l*2304,Wr+l*2304,Wm+l*2304,
          Wq+(l+1)*2304,Wk+(l+1)*2304,Wv+(l+1)*2304,nullptr,
          ATT,X,Qg16,Kg16,VgT,nullptr);
    } else {
      token_kernel<2><<<256,128,0,stream>>>(nullptr,nullptr,
          Wo+l*2304,Wl+l*2304,Wr+l*2304,Wm+l*2304,
          nullptr,nullptr,nullptr,Wout,
          ATT,X,nullptr,nullptr,nullptr,tok);
    }
  }
  reduce_kernel<<<1,256,0,stream>>>(tok,out);
}

// Round 13
// 646.717 us; speedup vs baseline: 1.1992x; 1.0475x over previous
//
#include <hip/hip_runtime.h>
#include <hip/hip_bf16.h>
#include <math.h>

#define NTOK 2048

typedef short short8v __attribute__((ext_vector_type(8)));
typedef short short4v __attribute__((ext_vector_type(4)));
typedef float f32x4 __attribute__((ext_vector_type(4)));
typedef unsigned u32x4 __attribute__((ext_vector_type(4)));

__device__ __forceinline__ unsigned short f2bf(float x){
  unsigned u = __float_as_uint(x);
  u += 0x7fff + ((u>>16)&1);           // round-to-nearest-even
  return (unsigned short)(u>>16);
}
__device__ __forceinline__ unsigned pack_bf2(float a, float b){
  __hip_bfloat162 h = __float22bfloat162_rn(float2{a,b});   // x -> low 16, y -> high 16
  return *reinterpret_cast<unsigned*>(&h);
}

// ---------------- compile-time G(3,0,1) tables ----------------
struct GEnt { unsigned char i, j, k; signed char s; };

constexpr int IDX2MASK[16] = {0,1,2,4,8,3,5,9,6,10,12,7,11,13,14,15};
constexpr int MASK2IDX[16] = {0,1,2,5,3,6,8,11,4,7,9,12,10,13,14,15};

constexpr int rsign(int a, int b){
  int cnt=0;
  for(int i=0;i<4;++i) if((b>>i)&1) for(int j=i+1;j<4;++j) if((a>>j)&1) cnt++;
  return (cnt&1)?-1:1;
}

struct GPTab { GEnt e[192]; };
constexpr GPTab make_gp(){
  GPTab t{}; int n=0;
  for(int ia=0; ia<16; ++ia) for(int ib=0; ib<16; ++ib){
    int a=IDX2MASK[ia], b=IDX2MASK[ib];
    if(a&b&1) continue;
    t.e[n].i=(unsigned char)ia; t.e[n].j=(unsigned char)ib;
    t.e[n].k=(unsigned char)MASK2IDX[a^b]; t.e[n].s=(signed char)rsign(a,b);
    ++n;
  }
  return t;
}
static constexpr GPTab GP_TAB = make_gp();

struct JTab { GEnt e[81]; };
constexpr JTab make_join(){
  JTab t{}; int n=0;
  for(int ia=0; ia<16; ++ia) for(int ib=0; ib<16; ++ib){
    int a=IDX2MASK[ia], b=IDX2MASK[ib];
    if((a|b)!=15) continue;
    int ca=(~a)&15, cb=(~b)&15, k=a&b, ck=(~k)&15;
    int s = rsign(a,ca)*rsign(b,cb)*rsign(ca,cb)*rsign(k,ck);
    t.e[n].i=(unsigned char)ia; t.e[n].j=(unsigned char)ib;
    t.e[n].k=(unsigned char)MASK2IDX[k]; t.e[n].s=(signed char)s;
    ++n;
  }
  return t;
}
static constexpr JTab J_TAB = make_join();

constexpr int INNER[8] = {0,2,3,4,8,9,10,14};

__device__ __forceinline__ void apply_gp(float* o, const float* a, const float* b){
#pragma unroll
  for(int n=0;n<192;++n){
    const float s = (float)GP_TAB.e[n].s;
    o[GP_TAB.e[n].k] = fmaf(s*a[GP_TAB.e[n].i], b[GP_TAB.e[n].j], o[GP_TAB.e[n].k]);
  }
}
__device__ __forceinline__ void apply_join(float* o, const float* a, const float* b){
#pragma unroll
  for(int n=0;n<81;++n){
    const float s = (float)J_TAB.e[n].s;
    o[J_TAB.e[n].k] = fmaf(s*a[J_TAB.e[n].i], b[J_TAB.e[n].j], o[J_TAB.e[n].k]);
  }
}

__device__ __forceinline__ float gelu_exact(float x){
  return 0.5f*x*(1.0f+erff(x*0.70710678118654752f));
}

// ---------------- token kernel: 64 workers/token (1 wave), i-split elins ----------------
// Worker (o, s): output channel o, input channels i in [4s, 4s+4). Partials combined
// across the s-bits (lane bits 4,5) by shfl_xor(16)+shfl_xor(32) -> every lane holds
// the full result. Norm sums via shfl_xor over the o-bits (1,2,4,8). Weights in LDS,
// layout [i][16 o][12] (b128-aligned rows, 2-way-free banks). Block=256 (4 tokens),
// grid=512 -> 2048 waves = 8 waves/CU (4x the old structure).
#define TBS 264

__device__ __forceinline__ void elin_part(float acc[16], const float* xin, const float* wslot, int o, int s){
#pragma unroll
  for(int j=0;j<16;++j) acc[j]=0.0f;
#pragma unroll
  for(int ii=0; ii<4; ++ii){
    int i = s*4 + ii;
    const float* w = wslot + (i*16 + o)*12;
    float4 wA = *(const float4*)(w);
    float4 wB = *(const float4*)(w+4);
    float w8 = w[8];
    const float4* xp = (const float4*)(xin + i*16);
    float4 A=xp[0], B=xp[1], Cc=xp[2], D=xp[3];
    float w0=wA.x,w1=wA.y,w2=wA.z,w3=wA.w,w4=wB.x,w5=wB.y,w6=wB.z,w7=wB.w;
    acc[0] = fmaf(w0, A.x,  acc[0]);
    acc[1] = fmaf(w1, A.y,  acc[1]);
    acc[2] = fmaf(w1, A.z,  acc[2]);
    acc[3] = fmaf(w1, A.w,  acc[3]);
    acc[4] = fmaf(w1, B.x,  acc[4]);
    acc[5] = fmaf(w2, B.y,  acc[5]);
    acc[6] = fmaf(w2, B.z,  acc[6]);
    acc[7] = fmaf(w2, B.w,  acc[7]);
    acc[8] = fmaf(w2, Cc.x, acc[8]);
    acc[9] = fmaf(w2, Cc.y, acc[9]);
    acc[10]= fmaf(w2, Cc.z, acc[10]);
    acc[11]= fmaf(w3, Cc.w, acc[11]);
    acc[12]= fmaf(w3, D.x,  acc[12]);
    acc[13]= fmaf(w3, D.y,  acc[13]);
    acc[14]= fmaf(w3, D.z,  acc[14]);
    acc[15]= fmaf(w4, D.w,  acc[15]);
    acc[1] = fmaf(w5, A.x,  acc[1]);
    acc[5] = fmaf(w6, A.z,  acc[5]);
    acc[6] = fmaf(w6, A.w,  acc[6]);
    acc[7] = fmaf(w6, B.x,  acc[7]);
    acc[11]= fmaf(w7, Cc.x, acc[11]);
    acc[12]= fmaf(w7, Cc.y, acc[12]);
    acc[13]= fmaf(w7, Cc.z, acc[13]);
    acc[15]= fmaf(w8, D.z,  acc[15]);
  }
}

__device__ __forceinline__ void combine16(float a[16]){
#pragma unroll
  for(int k=0;k<16;++k){
    a[k] += __shfl_xor(a[k],16);
    a[k] += __shfl_xor(a[k],32);
  }
}

__device__ __forceinline__ float normfac(const float xr[16]){
  float part=0;
#pragma unroll
  for(int z=0;z<8;++z){ float v=xr[INNER[z]]; part=fmaf(v,v,part); }
  part += __shfl_xor(part,1); part += __shfl_xor(part,2);
  part += __shfl_xor(part,4); part += __shfl_xor(part,8);
  return 1.0f/sqrtf(part*(1.0f/16.0f)+1e-6f);
}

#define LDSWAIT asm volatile("s_waitcnt lgkmcnt(0)" ::: "memory"); __builtin_amdgcn_sched_barrier(0);

template<int MODE>
__global__ __launch_bounds__(256) void token_kernel(
    const float* __restrict__ points, const float* __restrict__ Win,
    const float* __restrict__ Wo, const float* __restrict__ Wl,
    const float* __restrict__ Wr, const float* __restrict__ Wm,
    const float* __restrict__ Wq, const float* __restrict__ Wk,
    const float* __restrict__ Wv, const float* __restrict__ Wout,
    const float* __restrict__ ATT, float* __restrict__ X,
    unsigned short* __restrict__ Qg16, unsigned short* __restrict__ Kg16,
    unsigned short* __restrict__ VgT, float* __restrict__ toksum)
{
  __shared__ float wlds[4*3072];       // 4 slots x [16 i][16 o][12] = 49.2 KB
  __shared__ float buf[4*TBS];         // per-wave token vector
  const int tid = threadIdx.x;
  const int t = tid>>6, lane = tid&63;
  const int o = lane&15, s = lane>>4;
  const int n = blockIdx.x*4 + t;
  float* tb = buf + t*TBS;

  auto stage = [&](float* dst, const float* src){
#pragma unroll
    for(int r=0;r<9;++r){
      int k = tid + r*256;              // 2304 = 9*256
      int oo = k/144, rm = k%144, ii = rm/9, jj = rm%9;
      dst[(ii*16+oo)*12 + jj] = src[k];
    }
  };
  if (MODE==0){ stage(wlds+0*3072, Wq); stage(wlds+1*3072, Wk); stage(wlds+2*3072, Wv); }
  else        { stage(wlds+0*3072, Wo); stage(wlds+1*3072, Wl); stage(wlds+2*3072, Wr); stage(wlds+3*3072, Wm); }
  __syncthreads();

  float xr[16];

  if (MODE==0){
    float px = points[n*3+0], py = points[n*3+1], pz = points[n*3+2];
    float w3 = Win[o*9+3], w8e = Win[o*9+8];
#pragma unroll
    for(int j=0;j<16;++j) xr[j]=0.0f;
    xr[11]= w3*pz; xr[12]= -w3*py; xr[13]= w3*px; xr[14]= w3; xr[15]= w8e;
    if (s==0){
      float4* xg = (float4*)(X + (size_t)n*256 + o*16);
      xg[0]=make_float4(xr[0],xr[1],xr[2],xr[3]);
      xg[1]=make_float4(xr[4],xr[5],xr[6],xr[7]);
      xg[2]=make_float4(xr[8],xr[9],xr[10],xr[11]);
      xg[3]=make_float4(xr[12],xr[13],xr[14],xr[15]);
    }
  } else {
    const float4* xg = (const float4*)(X + (size_t)n*256 + o*16);
    float4 a=xg[0],b=xg[1],c=xg[2],d=xg[3];
    xr[0]=a.x; xr[1]=a.y; xr[2]=a.z; xr[3]=a.w;
    xr[4]=b.x; xr[5]=b.y; xr[6]=b.z; xr[7]=b.w;
    xr[8]=c.x; xr[9]=c.y; xr[10]=c.z; xr[11]=c.w;
    xr[12]=d.x; xr[13]=d.y; xr[14]=d.z; xr[15]=d.w;
    if (s==0){
      const float4* ag = (const float4*)(ATT + (size_t)n*256 + o*16);
      float4* bp = (float4*)(tb + o*16);
      bp[0]=ag[0]; bp[1]=ag[1]; bp[2]=ag[2]; bp[3]=ag[3];
    }
    LDSWAIT
    float acc[16];
    elin_part(acc, tb, wlds+0*3072, o, s);   // Wo
    combine16(acc);
#pragma unroll
    for(int j=0;j<16;++j) xr[j]+=acc[j];
    // --- norm 1 ---
    float f = normfac(xr);
    if (s==0){
      float4* bp=(float4*)(tb+o*16);
      bp[0]=make_float4(xr[0]*f,xr[1]*f,xr[2]*f,xr[3]*f);
      bp[1]=make_float4(xr[4]*f,xr[5]*f,xr[6]*f,xr[7]*f);
      bp[2]=make_float4(xr[8]*f,xr[9]*f,xr[10]*f,xr[11]*f);
      bp[3]=make_float4(xr[12]*f,xr[13]*f,xr[14]*f,xr[15]*f);
    }
    LDSWAIT
    // --- MLP ---
    float L[16], R[16];
    elin_part(L, tb, wlds+1*3072, o, s); combine16(L);
    elin_part(R, tb, wlds+2*3072, o, s); combine16(R);
    float h[16];
#pragma unroll
    for(int j=0;j<16;++j) h[j]=0.0f;
    if (o<8) apply_gp(h,L,R); else apply_join(h,L,R);
    float gel = gelu_exact(h[0]);
#pragma unroll
    for(int j=0;j<16;++j) h[j]*=gel;
    if (s==0){
      float4* bp=(float4*)(tb+o*16);
      bp[0]=make_float4(h[0],h[1],h[2],h[3]);
      bp[1]=make_float4(h[4],h[5],h[6],h[7]);
      bp[2]=make_float4(h[8],h[9],h[10],h[11]);
      bp[3]=make_float4(h[12],h[13],h[14],h[15]);
    }
    LDSWAIT
    float mm[16];
    elin_part(mm, tb, wlds+3*3072, o, s); combine16(mm);
#pragma unroll
    for(int j=0;j<16;++j) xr[j]+=mm[j];
    if (MODE==1 && s==0){
      float4* xs = (float4*)(X + (size_t)n*256 + o*16);
      xs[0]=make_float4(xr[0],xr[1],xr[2],xr[3]);
      xs[1]=make_float4(xr[4],xr[5],xr[6],xr[7]);
      xs[2]=make_float4(xr[8],xr[9],xr[10],xr[11]);
      xs[3]=make_float4(xr[12],xr[13],xr[14],xr[15]);
    }
  }

  if (MODE==2){
    float val = Wout[o*9]*xr[0];
    val += __shfl_xor(val,1); val += __shfl_xor(val,2);
    val += __shfl_xor(val,4); val += __shfl_xor(val,8);
    if (lane==0) toksum[n]=val;
    return;
  }

  // ---- restage QKV weights (MODE 1) ----
  if (MODE==1){
    __syncthreads();                   // all waves done reading slots 0-2
    stage(wlds+0*3072, Wq); stage(wlds+1*3072, Wk); stage(wlds+2*3072, Wv);
    __syncthreads();
  }

  // ---- norm 2 + QKV ----
  {
    float f2 = normfac(xr);
    if (s==0){
      float4* bp=(float4*)(tb+o*16);
      bp[0]=make_float4(xr[0]*f2,xr[1]*f2,xr[2]*f2,xr[3]*f2);
      bp[1]=make_float4(xr[4]*f2,xr[5]*f2,xr[6]*f2,xr[7]*f2);
      bp[2]=make_float4(xr[8]*f2,xr[9]*f2,xr[10]*f2,xr[11]*f2);
      bp[3]=make_float4(xr[12]*f2,xr[13]*f2,xr[14]*f2,xr[15]*f2);
    }
    LDSWAIT
    float q_[16],k_[16],v_[16];
    elin_part(q_, tb, wlds+0*3072, o, s); combine16(q_);
    elin_part(k_, tb, wlds+1*3072, o, s); combine16(k_);
    elin_part(v_, tb, wlds+2*3072, o, s); combine16(v_);
    int hh=o>>1, cc=o&1;
    size_t rb = ((size_t)hh*NTOK + n)*16 + cc*8;
    if (s==0){
      unsigned qw[4];
#pragma unroll
      for(int j=0;j<4;++j) qw[j] = pack_bf2(q_[INNER[2*j]]*0.25f, q_[INNER[2*j+1]]*0.25f);
      *(uint4*)(Qg16 + rb) = make_uint4(qw[0],qw[1],qw[2],qw[3]);
    } else if (s==1){
      unsigned kw[4];
#pragma unroll
      for(int j=0;j<4;++j) kw[j] = pack_bf2(k_[INNER[2*j]], k_[INNER[2*j+1]]);
      *(uint4*)(Kg16 + rb) = make_uint4(kw[0],kw[1],kw[2],kw[3]);
    }
    if (s==0){
      float4* bp=(float4*)(tb+o*16);
      bp[0]=make_float4(v_[0],v_[1],v_[2],v_[3]);
      bp[1]=make_float4(v_[4],v_[5],v_[6],v_[7]);
      bp[2]=make_float4(v_[8],v_[9],v_[10],v_[11]);
      bp[3]=make_float4(v_[12],v_[13],v_[14],v_[15]);
    }
  }
  __syncthreads();                     // cross-wave: transpose gathers all 4 tokens
  {
    int row = tid;                     // 256 rows = [h2 32][v2]
    int h2 = row>>5, v2 = row&31;
    int oc = 2*h2 + (v2>>4), c2 = v2&15;
    float v0 = buf[0*TBS + oc*16 + c2];
    float v1 = buf[1*TBS + oc*16 + c2];
    float v2f= buf[2*TBS + oc*16 + c2];
    float v3f= buf[3*TBS + oc*16 + c2];
    uint2 out;
    out.x = pack_bf2(v0,v1);
    out.y = pack_bf2(v2f,v3f);
    *(uint2*)(VgT + (size_t)row*NTOK + blockIdx.x*4) = out;
  }
}

// ---------------- MFMA flash attention (round-12 version, validated) ----------------
__global__ __launch_bounds__(512, 8) void attn_kernel(
    const unsigned short* __restrict__ Qg16, const unsigned short* __restrict__ Kg16,
    const unsigned short* __restrict__ VgT,  float* __restrict__ ATT)
{
  __shared__ float cmb[8*32*17];
  __shared__ float ml[8*16*2];
  const int tid = threadIdx.x;
  const int l   = tid & 63, w = tid >> 6;
  const int h   = blockIdx.x >> 7, qb = blockIdx.x & 127;
  const int l15 = l & 15, lg = l >> 4;

  const short4v z4 = {0,0,0,0};
  short8v qf;
  {
    const short4v* qp = (const short4v*)(Qg16 + ((size_t)(h*NTOK + qb*16 + l15))*16 + lg*4);
    qf = __builtin_shufflevector(*qp, z4, 0,1,2,3,4,5,6,7);
  }

  const int key0 = w*256;
  const size_t vrow = ((size_t)(h*32 + l15))*NTOK;

  float mx = -INFINITY;
#pragma unroll 1
  for(int kc=0; kc<256; kc+=64){
#pragma unroll
    for(int t2=0;t2<4;++t2){
      const short4v* kp = (const short4v*)(Kg16 + ((size_t)(h*NTOK + key0 + kc + t2*16 + l15))*16 + lg*4);
      short8v kf = __builtin_shufflevector(*kp, z4, 0,1,2,3,4,5,6,7);
      f32x4 z = {0,0,0,0};
      f32x4 S = __builtin_amdgcn_mfma_f32_16x16x32_bf16(kf, qf, z, 0,0,0);
      mx = fmaxf(mx, fmaxf(fmaxf(S[0],S[1]), fmaxf(S[2],S[3])));
    }
  }
  mx = fmaxf(mx, __shfl_xor(mx, 16));
  mx = fmaxf(mx, __shfl_xor(mx, 32));
  const float M = mx;

  f32x4 acc0 = {0,0,0,0}, acc1 = {0,0,0,0};
  float ls = 0.0f;
#pragma unroll 1
  for(int kc=0; kc<256; kc+=64){
    f32x4 S[4];
#pragma unroll
    for(int t2=0;t2<4;++t2){
      const short4v* kp = (const short4v*)(Kg16 + ((size_t)(h*NTOK + key0 + kc + t2*16 + l15))*16 + lg*4);
      short8v kf = __builtin_shufflevector(*kp, z4, 0,1,2,3,4,5,6,7);
      f32x4 z = {0,0,0,0};
      S[t2] = __builtin_amdgcn_mfma_f32_16x16x32_bf16(kf, qf, z, 0,0,0);
    }
    float p[4][4];
#pragma unroll
    for(int t2=0;t2<4;++t2)
#pragma unroll
      for(int r=0;r<4;++r){ float pv = __expf(S[t2][r]-M); p[t2][r]=pv; ls += pv; }
    u32x4 paw, paw2;
    paw[0]=pack_bf2(p[0][0],p[0][1]); paw[1]=pack_bf2(p[0][2],p[0][3]);
    paw[2]=pack_bf2(p[1][0],p[1][1]); paw[3]=pack_bf2(p[1][2],p[1][3]);
    paw2[0]=pack_bf2(p[2][0],p[2][1]); paw2[1]=pack_bf2(p[2][2],p[2][3]);
    paw2[2]=pack_bf2(p[3][0],p[3][1]); paw2[3]=pack_bf2(p[3][2],p[3][3]);
    short8v pa  = *reinterpret_cast<short8v*>(&paw);
    short8v pa2 = *reinterpret_cast<short8v*>(&paw2);
    size_t vb = vrow + key0 + kc;
    const short4v* v0a = (const short4v*)(VgT + vb + lg*4);
    const short4v* v0b = (const short4v*)(VgT + vb + 16 + lg*4);
    const short4v* v0c = (const short4v*)(VgT + vb + 32 + lg*4);
    const short4v* v0d = (const short4v*)(VgT + vb + 48 + lg*4);
    short8v vb0  = __builtin_shufflevector(*v0a, *v0b, 0,1,2,3,4,5,6,7);
    short8v vb0b = __builtin_shufflevector(*v0c, *v0d, 0,1,2,3,4,5,6,7);
    size_t vb1s = vb + (size_t)16*NTOK;
    const short4v* v1a = (const short4v*)(VgT + vb1s + lg*4);
    const short4v* v1b = (const short4v*)(VgT + vb1s + 16 + lg*4);
    const short4v* v1c = (const short4v*)(VgT + vb1s + 32 + lg*4);
    const short4v* v1d = (const short4v*)(VgT + vb1s + 48 + lg*4);
    short8v vb1  = __builtin_shufflevector(*v1a, *v1b, 0,1,2,3,4,5,6,7);
    short8v vb1b = __builtin_shufflevector(*v1c, *v1d, 0,1,2,3,4,5,6,7);
    acc0 = __builtin_amdgcn_mfma_f32_16x16x32_bf16(pa,  vb0,  acc0, 0,0,0);
    acc0 = __builtin_amdgcn_mfma_f32_16x16x32_bf16(pa2, vb0b, acc0, 0,0,0);
    acc1 = __builtin_amdgcn_mfma_f32_16x16x32_bf16(pa,  vb1,  acc1, 0,0,0);
    acc1 = __builtin_amdgcn_mfma_f32_16x16x32_bf16(pa2, vb1b, acc1, 0,0,0);
  }
  ls += __shfl_xor(ls, 16);
  ls += __shfl_xor(ls, 32);

  {
    float* cw = cmb + w*544;
#pragma unroll
    for(int r=0;r<4;++r){
      cw[ l15     *17 + lg*4 + r] = acc0[r];
      cw[(l15+16) *17 + lg*4 + r] = acc1[r];
    }
    if (lg == 0){
      ml[(w*16 + l15)*2]   = M;
      ml[(w*16 + l15)*2+1] = ls;
    }
  }
  __syncthreads();
  {
    int q = tid & 15, v = tid >> 4;
    float Mg = -INFINITY;
#pragma unroll
    for(int w2=0; w2<8; ++w2) Mg = fmaxf(Mg, ml[(w2*16+q)*2]);
    float L=0, a=0;
#pragma unroll
    for(int w2=0; w2<8; ++w2){
      float ww = __expf(ml[(w2*16+q)*2] - Mg);
      L = fmaf(ml[(w2*16+q)*2+1], ww, L);
      a = fmaf(cmb[w2*544 + v*17 + q], ww, a);
    }
    int n = qb*16 + q;
    ATT[(size_t)n*256 + (size_t)(2*h + (v>>4))*16 + (v&15)] = a/L;
  }
}

__global__ __launch_bounds__(256) void reduce_kernel(const float* __restrict__ tok, float* __restrict__ out){
  int tid=threadIdx.x;
  float s=0;
  for(int i=tid;i<NTOK;i+=256) s+=tok[i];
#pragma unroll
  for(int off=32;off>0;off>>=1) s += __shfl_down(s,off);
  __shared__ float red[4];
  if((tid&63)==0) red[tid>>6]=s;
  __syncthreads();
  if(tid==0) out[0]=(red[0]+red[1]+red[2]+red[3])*(1.0f/2048.0f);
}

extern "C" void kernel_launch(void* const* d_in, const int* in_sizes, int n_in,
                              void* d_out, int out_size, void* d_ws, size_t ws_size,
                              hipStream_t stream){
  const float* points=(const float*)d_in[0];
  const float* Win=(const float*)d_in[1];
  const float* Wq=(const float*)d_in[2];
  const float* Wk=(const float*)d_in[3];
  const float* Wv=(const float*)d_in[4];
  const float* Wo=(const float*)d_in[5];
  const float* Wl=(const float*)d_in[6];
  const float* Wr=(const float*)d_in[7];
  const float* Wm=(const float*)d_in[8];
  const float* Wout=(const float*)d_in[9];
  float* ws=(float*)d_ws;
  float* X    = ws;                                         // 524288 f
  float* ATT  = ws + 524288;                                // 524288 f
  unsigned short* Qg16 = (unsigned short*)(ws + 1048576);   // 262144 us
  unsigned short* Kg16 = (unsigned short*)(ws + 1179648);   // 262144 us
  unsigned short* VgT  = (unsigned short*)(ws + 1310720);   // 524288 us
  float* tok  = ws + 1572864;
  float* out=(float*)d_out;

  token_kernel<0><<<512,256,0,stream>>>(points,Win,nullptr,nullptr,nullptr,nullptr,
                                        Wq,Wk,Wv,nullptr,nullptr,X,Qg16,Kg16,VgT,nullptr);
  for(int l=0;l<10;++l){
    attn_kernel<<<1024,512,0,stream>>>(Qg16,Kg16,VgT,ATT);
    if(l<9){
      token_kernel<1><<<512,256,0,stream>>>(nullptr,nullptr,
          Wo+l*2304,Wl+l*2304,Wr+l*2304,Wm+l*2304,
          Wq+(l+1)*2304,Wk+(l+1)*2304,Wv+(l+1)*2304,nullptr,
          ATT,X,Qg16,Kg16,VgT,nullptr);
    } else {
      token_kernel<2><<<512,256,0,stream>>>(nullptr,nullptr,
          Wo+l*2304,Wl+l*2304,Wr+l*2304,Wm+l*2304,
          nullptr,nullptr,nullptr,Wout,
          ATT,X,nullptr,nullptr,nullptr,tok);
    }
  }
  reduce_kernel<<<1,256,0,stream>>>(tok,out);
}